// Round 5
// baseline (495.268 us; speedup 1.0000x reference)
//
#include <hip/hip_runtime.h>

// MLPPredictor as bf16 MFMA GEMM: C[E,10] = concat(h[src],h[dst],eh)[E,384] x W^T + b
// Round 5: no-LDS design. Round 4 paid, per 37500 blocks: full weight
// reload+cvt, LDS round-trip, barrier. Now:
//  - prep kernel builds bf16 B-fragments ONCE into d_ws as frag[t][lane]
//    (main kernel: 12 coalesced 16B loads -> 48 VGPRs, L2-broadcast).
//  - A-fragments loaded DIRECTLY global->VGPR: lane l = row (base + l&15),
//    k-offset (l>>4)*8; two contiguous float4 per K-step. No LDS, no barrier.
//  - 4 tiles (64 edges) per wave; 3-group pipeline per tile (<=16 float4 in
//    flight) so dst/eh loads fly during src-group MFMAs.

typedef __attribute__((ext_vector_type(8))) short short8;
typedef __attribute__((ext_vector_type(4))) float f32x4;

#define NC   10
#define TPW  4            // 16-edge tiles per wave
#define NFRAG 12          // K=384 / 32

__device__ __forceinline__ unsigned short f2bf(float f) {
    unsigned u = __builtin_bit_cast(unsigned, f);
    u += 0x7FFFu + ((u >> 16) & 1u);          // round-to-nearest-even
    return (unsigned short)(u >> 16);
}

__device__ __forceinline__ short8 cvt8(f32x4 a, f32x4 b) {
    short8 s;
    s[0]=(short)f2bf(a[0]); s[1]=(short)f2bf(a[1]);
    s[2]=(short)f2bf(a[2]); s[3]=(short)f2bf(a[3]);
    s[4]=(short)f2bf(b[0]); s[5]=(short)f2bf(b[1]);
    s[6]=(short)f2bf(b[2]); s[7]=(short)f2bf(b[3]);
    return s;
}

// ---- prep: build B-fragments frag[t*64 + lane] from Ww (runs once, 1 block) ----
__global__ void build_wfrag(const float* __restrict__ Ww, short8* __restrict__ frag) {
    const int l = threadIdx.x;            // 0..63
    const int n = l & 15;                 // class column
    const int q = l >> 4;                 // k-quad
#pragma unroll
    for (int t = 0; t < NFRAG; ++t) {
        short8 b = (short8)0;
        if (n < NC) {
            const float* w = Ww + n * 384 + t * 32 + q * 8;
            const f32x4 w0 = *(const f32x4*)(w);
            const f32x4 w1 = *(const f32x4*)(w + 4);
            b = cvt8(w0, w1);
        }
        frag[t * 64 + l] = b;
    }
}

// load one 4-step K-group (128 floats of a row; this lane's 8 float4s)
#define LG(v0,v1,v2,v3,v4,v5,v6,v7,p)           \
    v0 = *(const f32x4*)((p) + 0);              \
    v1 = *(const f32x4*)((p) + 4);              \
    v2 = *(const f32x4*)((p) + 32);             \
    v3 = *(const f32x4*)((p) + 36);             \
    v4 = *(const f32x4*)((p) + 64);             \
    v5 = *(const f32x4*)((p) + 68);             \
    v6 = *(const f32x4*)((p) + 96);             \
    v7 = *(const f32x4*)((p) + 100);

// consume one group: 4 cvt+MFMA steps against fragments g*4..g*4+3
#define CG(g, v0,v1,v2,v3,v4,v5,v6,v7)                                        \
    acc = __builtin_amdgcn_mfma_f32_16x16x32_bf16(cvt8(v0,v1), bf[(g)*4+0], acc, 0,0,0); \
    acc = __builtin_amdgcn_mfma_f32_16x16x32_bf16(cvt8(v2,v3), bf[(g)*4+1], acc, 0,0,0); \
    acc = __builtin_amdgcn_mfma_f32_16x16x32_bf16(cvt8(v4,v5), bf[(g)*4+2], acc, 0,0,0); \
    acc = __builtin_amdgcn_mfma_f32_16x16x32_bf16(cvt8(v6,v7), bf[(g)*4+3], acc, 0,0,0);

__global__ __launch_bounds__(64, 3) void mlp_edge_mfma(
    const float* __restrict__ h,      // [N,128]
    const float* __restrict__ eh,     // [E,128]
    const short8* __restrict__ frag,  // [12*64] prebuilt B-fragments
    const float* __restrict__ Wb,     // [10]
    const int*   __restrict__ src,    // [E]
    const int*   __restrict__ dst,    // [E]
    float* __restrict__ out,          // [E,10]
    int E)
{
    const int l = threadIdx.x;        // 0..63
    const int n = l & 15;             // A-row (edge-in-tile) AND B-col (class)
    const int q = l >> 4;             // k-quad: k = q*8 + j

    // B-fragments: 12 coalesced 16B loads, resident for all 4 tiles
    short8 bf[NFRAG];
#pragma unroll
    for (int t = 0; t < NFRAG; ++t) bf[t] = frag[t * 64 + l];
    const float bias = (n < NC) ? Wb[n] : 0.f;

    const long tile0 = (long)blockIdx.x * TPW;

#pragma unroll 1
    for (int tt = 0; tt < TPW; ++tt) {
        const long base = (tile0 + tt) * 16;
        if (base >= E) break;                       // uniform
        const long e  = base + n;
        const long ec = (e < E) ? e : (long)(E - 1);
        const float* ps = h  + (long)src[ec] * 128 + q * 8;
        const float* pd = h  + (long)dst[ec] * 128 + q * 8;
        const float* pe = eh + ec * 128 + q * 8;

        f32x4 x0,x1,x2,x3,x4,x5,x6,x7;    // group buffer A
        f32x4 y0,y1,y2,y3,y4,y5,y6,y7;    // group buffer B

        f32x4 acc = {0.f, 0.f, 0.f, 0.f};

        LG(x0,x1,x2,x3,x4,x5,x6,x7, ps)   // src group in flight
        LG(y0,y1,y2,y3,y4,y5,y6,y7, pd)   // dst group in flight
        CG(0, x0,x1,x2,x3,x4,x5,x6,x7)    // compute src
        LG(x0,x1,x2,x3,x4,x5,x6,x7, pe)   // eh group in flight (reuse regs)
        CG(1, y0,y1,y2,y3,y4,y5,y6,y7)    // compute dst
        CG(2, x0,x1,x2,x3,x4,x5,x6,x7)    // compute eh

        // C/D: col = n = lane&15 (class), row(edge-in-tile) = q*4 + r
        if (n < NC) {
#pragma unroll
            for (int r = 0; r < 4; ++r) {
                const long e2 = base + q * 4 + r;
                if (e2 < E) out[e2 * NC + n] = acc[r] + bias;
            }
        }
    }
}

extern "C" void kernel_launch(void* const* d_in, const int* in_sizes, int n_in,
                              void* d_out, int out_size, void* d_ws, size_t ws_size,
                              hipStream_t stream) {
    const float* h   = (const float*)d_in[0];
    const float* eh  = (const float*)d_in[1];
    const float* Ww  = (const float*)d_in[2];
    const float* Wb  = (const float*)d_in[3];
    const int*   src = (const int*)d_in[4];
    const int*   dst = (const int*)d_in[5];
    float* out = (float*)d_out;

    const int E = in_sizes[4];
    short8* frag = (short8*)d_ws;                  // 12*64*16 = 12288 B scratch

    build_wfrag<<<1, 64, 0, stream>>>(Ww, frag);   // same stream -> ordered

    const int edgesPerBlock = 16 * TPW;            // 64
    const int blocks = (E + edgesPerBlock - 1) / edgesPerBlock;  // 9375
    mlp_edge_mfma<<<blocks, 64, 0, stream>>>(h, eh, frag, Wb, src, dst, out, E);
}

// Round 6
// 490.820 us; speedup vs baseline: 1.0091x; 1.0091x over previous
//
#include <hip/hip_runtime.h>

// MLPPredictor as bf16 MFMA GEMM: C[E,10] = concat(h[src],h[dst],eh)[E,384] x W^T + b
// Round 6: async-DMA design. Rounds 4/5 plateaued ~170us because in-flight
// load bytes (VGPR-bound: ~16 float4/wave x 12 waves = 3KB/CU) x latency
// caps effective BW at ~5 TB/s. global_load_lds costs NO VGPRs:
//  - 1 wave/block, 8 tiles (128 edges)/wave, 3 x 8KB LDS group buffers.
//  - per group: 8 DMA instrs; lane l -> row l&15, chunk l>>4; LDS layout
//    [i][w][r] matches the wave-uniform-base + lane*16 DMA rule exactly.
//  - manual s_waitcnt vmcnt(16/8/0): always 2 groups (16KB) in flight/wave.
//  - A-frag read-back: two ds_read_b128, banks (n*4+j)%32 -> 2-way only (free).
//  - B-fragments prebuilt once into d_ws (round-5 prep kernel, unchanged).
//  - indices preloaded, accs held to wave end => vmcnt arithmetic is exact.

typedef __attribute__((ext_vector_type(8))) short short8;
typedef __attribute__((ext_vector_type(4))) float f32x4;

#define NC    10
#define TPW   8            // 16-edge tiles per wave
#define NFRAG 12           // K=384 / 32

// wait until <= N vector-memory ops outstanding (lgkm/exp unconstrained)
#define WAITVM(N) __builtin_amdgcn_s_waitcnt(((N)&0xF) | (7u<<4) | (0xFu<<8) | (((unsigned)(N)>>4)<<14))

__device__ __forceinline__ unsigned short f2bf(float f) {
    unsigned u = __builtin_bit_cast(unsigned, f);
    u += 0x7FFFu + ((u >> 16) & 1u);          // round-to-nearest-even
    return (unsigned short)(u >> 16);
}

__device__ __forceinline__ short8 cvt8(f32x4 a, f32x4 b) {
    short8 s;
    s[0]=(short)f2bf(a[0]); s[1]=(short)f2bf(a[1]);
    s[2]=(short)f2bf(a[2]); s[3]=(short)f2bf(a[3]);
    s[4]=(short)f2bf(b[0]); s[5]=(short)f2bf(b[1]);
    s[6]=(short)f2bf(b[2]); s[7]=(short)f2bf(b[3]);
    return s;
}

__device__ __forceinline__ void dma16(const void* g, void* l) {
    __builtin_amdgcn_global_load_lds(
        (const __attribute__((address_space(1))) void*)g,
        (__attribute__((address_space(3))) void*)l,
        16, 0, 0);
}

// ---- prep: build B-fragments frag[t*64 + lane] from Ww (runs once, 1 block) ----
__global__ void build_wfrag(const float* __restrict__ Ww, short8* __restrict__ frag) {
    const int l = threadIdx.x;
    const int n = l & 15;
    const int q = l >> 4;
#pragma unroll
    for (int t = 0; t < NFRAG; ++t) {
        short8 b = (short8)0;
        if (n < NC) {
            const float* w = Ww + n * 384 + t * 32 + q * 8;
            b = cvt8(*(const f32x4*)w, *(const f32x4*)(w + 4));
        }
        frag[t * 64 + l] = b;
    }
}

__global__ __launch_bounds__(64, 2) void mlp_edge_dma(
    const float* __restrict__ h,      // [N,128]
    const float* __restrict__ eh,     // [E,128]
    const short8* __restrict__ frag,  // [12*64] prebuilt B-fragments
    const float* __restrict__ Wb,     // [10]
    const int*   __restrict__ src,    // [E]
    const int*   __restrict__ dst,    // [E]
    float* __restrict__ out,          // [E,10]
    int E)
{
    __shared__ __align__(16) char buf[3][8192];   // 3 group buffers, 24 KB

    const int l = threadIdx.x;        // 0..63
    const int n = l & 15;             // MFMA: A-row (edge) / B-col (class); DMA row
    const int q = l >> 4;             // MFMA k-quad; DMA 16B-chunk index w

    const long wbase = (long)blockIdx.x * (16 * TPW);

    // B-fragments: 12 coalesced 16B loads, resident for all 8 tiles
    short8 bf[NFRAG];
#pragma unroll
    for (int t = 0; t < NFRAG; ++t) bf[t] = frag[t * 64 + l];
    const float bias = (n < NC) ? Wb[n] : 0.f;

    // preload gather indices for all 8 tiles (lane uses row r = n)
    int sidx[TPW], didx[TPW], erow[TPW];
#pragma unroll
    for (int t = 0; t < TPW; ++t) {
        const long er  = wbase + t * 16 + n;
        const long erc = (er < E) ? er : (long)(E - 1);
        sidx[t] = src[erc];
        didx[t] = dst[erc];
        erow[t] = (int)erc;
    }

    f32x4 acc[TPW];
#pragma unroll
    for (int t = 0; t < TPW; ++t) acc[t] = (f32x4){0.f, 0.f, 0.f, 0.f};

    const unsigned wb16 = (unsigned)q * 16u;   // chunk byte offset within 64B row-piece

// issue one K-group (16 rows x 128 floats) of tile t, source s, into buf[s]
#define ISSUE_G(t, s) do {                                                    \
    const char* gb;                                                           \
    unsigned off;                                                             \
    if ((s) == 0)      { gb = (const char*)h;  off = (unsigned)sidx[t] * 512u + wb16; } \
    else if ((s) == 1) { gb = (const char*)h;  off = (unsigned)didx[t] * 512u + wb16; } \
    else               { gb = (const char*)eh; off = (unsigned)erow[t] * 512u + wb16; } \
    const char* ga = gb + off;                                                \
    char* lb = &buf[(s)][0];                                                  \
    _Pragma("unroll")                                                         \
    for (int i = 0; i < 8; ++i) dma16(ga + i * 64, lb + i * 1024);            \
} while (0)

// consume buf[s] against fragment block s for tile t (4 MFMA steps)
#define CONSUME_G(t, s) do {                                                  \
    const char* lb = &buf[(s)][0];                                            \
    _Pragma("unroll")                                                         \
    for (int t4 = 0; t4 < 4; ++t4) {                                          \
        const int ib = (2 * t4 + (q >> 1)) * 1024 + ((q & 1) * 2) * 256 + n * 16; \
        const f32x4 a0 = *(const f32x4*)(lb + ib);                            \
        const f32x4 a1 = *(const f32x4*)(lb + ib + 256);                      \
        acc[t] = __builtin_amdgcn_mfma_f32_16x16x32_bf16(                     \
            cvt8(a0, a1), bf[(s) * 4 + t4], acc[t], 0, 0, 0);                 \
    }                                                                         \
} while (0)

    // drain preloads so vmcnt arithmetic below is exact
    WAITVM(0);
    __asm__ volatile("" ::: "memory");

    ISSUE_G(0, 0); ISSUE_G(0, 1); ISSUE_G(0, 2);   // 24 DMAs outstanding

#pragma unroll
    for (int t = 0; t < TPW; ++t) {
#pragma unroll
        for (int s = 0; s < 3; ++s) {
            if (t < TPW - 1 || s == 0) { WAITVM(16); }   // oldest group landed
            else if (s == 1)           { WAITVM(8);  }   // tail drain
            else                       { WAITVM(0);  }
            __asm__ volatile("" ::: "memory");
            CONSUME_G(t, s);
            if (t < TPW - 1) ISSUE_G(t + 1, s);          // refill freed buffer
        }
    }
#undef ISSUE_G
#undef CONSUME_G

    // epilogue: C/D col = n (class), row(edge-in-tile) = q*4 + r
    if (n < NC) {
#pragma unroll
        for (int t = 0; t < TPW; ++t) {
            const long tb = wbase + t * 16;
#pragma unroll
            for (int r = 0; r < 4; ++r) {
                const long e2 = tb + q * 4 + r;
                if (e2 < E) out[e2 * NC + n] = acc[t][r] + bias;
            }
        }
    }
}

extern "C" void kernel_launch(void* const* d_in, const int* in_sizes, int n_in,
                              void* d_out, int out_size, void* d_ws, size_t ws_size,
                              hipStream_t stream) {
    const float* h   = (const float*)d_in[0];
    const float* eh  = (const float*)d_in[1];
    const float* Ww  = (const float*)d_in[2];
    const float* Wb  = (const float*)d_in[3];
    const int*   src = (const int*)d_in[4];
    const int*   dst = (const int*)d_in[5];
    float* out = (float*)d_out;

    const int E = in_sizes[4];
    short8* frag = (short8*)d_ws;                  // 12*64*16 = 12288 B scratch

    build_wfrag<<<1, 64, 0, stream>>>(Ww, frag);   // same stream -> ordered

    const int edgesPerBlock = 16 * TPW;            // 128
    const int blocks = (E + edgesPerBlock - 1) / edgesPerBlock;  // 4688
    mlp_edge_dma<<<blocks, 64, 0, stream>>>(h, eh, frag, Wb, src, dst, out, E);
}

// Round 7
// 484.903 us; speedup vs baseline: 1.0214x; 1.0122x over previous
//
#include <hip/hip_runtime.h>

// MLPPredictor as bf16 MFMA GEMM: C[E,10] = concat(h[src],h[dst],eh)[E,384] x W^T + b
// Round 7: r3-r6 all converge at 2.3-2.8 TB/s => the wall is per-instruction
// gather processing (each 1KB load spans 16 scattered 64B lines; ~135 cy/instr
// measured r6) / per-CU miss concurrency. Levers: fewer gather instructions,
// fewer logical bytes, shorter latency. So:
//  - prep kernel converts h to a bf16 table in d_ws (26 MB: L3-resident,
//    ~13us). One h K-group = 4 instrs (was 8), h logical bytes halved,
//    h-side cvt VALU eliminated (LDS-free, data is MFMA-ready).
//  - eh stays f32 streaming (pre-converting it costs more than it saves).
//  - r5's register pipeline, issue src->dst->eh, consume same order (eh,
//    the real HBM stream, gets the longest time in flight).
//  - f32-h fallback template if ws_size can't hold the table.

typedef __attribute__((ext_vector_type(8))) short short8;
typedef __attribute__((ext_vector_type(4))) float f32x4;

#define NC    10
#define TPW   4            // 16-edge tiles per wave
#define NFRAG 12           // K=384 / 32
#define FRAG_BYTES 12288   // 12*64*16

__device__ __forceinline__ unsigned short f2bf(float f) {
    unsigned u = __builtin_bit_cast(unsigned, f);
    u += 0x7FFFu + ((u >> 16) & 1u);          // round-to-nearest-even
    return (unsigned short)(u >> 16);
}

__device__ __forceinline__ short8 cvt8(f32x4 a, f32x4 b) {
    short8 s;
    s[0]=(short)f2bf(a[0]); s[1]=(short)f2bf(a[1]);
    s[2]=(short)f2bf(a[2]); s[3]=(short)f2bf(a[3]);
    s[4]=(short)f2bf(b[0]); s[5]=(short)f2bf(b[1]);
    s[6]=(short)f2bf(b[2]); s[7]=(short)f2bf(b[3]);
    return s;
}

// ---- prep 1: B-fragments frag[t*64 + lane] from Ww (1 block, once) ----
__global__ void build_wfrag(const float* __restrict__ Ww, short8* __restrict__ frag) {
    const int l = threadIdx.x;
    const int n = l & 15;
    const int q = l >> 4;
#pragma unroll
    for (int t = 0; t < NFRAG; ++t) {
        short8 b = (short8)0;
        if (n < NC) {
            const float* w = Ww + n * 384 + t * 32 + q * 8;
            b = cvt8(*(const f32x4*)w, *(const f32x4*)(w + 4));
        }
        frag[t * 64 + l] = b;
    }
}

// ---- prep 2: h (f32) -> bf16 table; thread converts 8 floats ----
__global__ __launch_bounds__(256) void cvt_h_kernel(
    const float* __restrict__ h, short8* __restrict__ hb, long n8) {
    const long i = (long)blockIdx.x * 256 + threadIdx.x;
    if (i < n8) {
        const f32x4 a = *(const f32x4*)(h + i * 8);
        const f32x4 b = *(const f32x4*)(h + i * 8 + 4);
        hb[i] = cvt8(a, b);
    }
}

#define LGF(v0,v1,v2,v3,v4,v5,v6,v7,p)          \
    v0 = *(const f32x4*)((p) + 0);              \
    v1 = *(const f32x4*)((p) + 4);              \
    v2 = *(const f32x4*)((p) + 32);             \
    v3 = *(const f32x4*)((p) + 36);             \
    v4 = *(const f32x4*)((p) + 64);             \
    v5 = *(const f32x4*)((p) + 68);             \
    v6 = *(const f32x4*)((p) + 96);             \
    v7 = *(const f32x4*)((p) + 100);

template<bool BF16H>
__global__ __launch_bounds__(64, 3) void mlp_edge_mfma(
    const float* __restrict__ h,             // [N,128] f32 (fallback path)
    const unsigned short* __restrict__ hb,   // [N,128] bf16 table (main path)
    const float* __restrict__ eh,            // [E,128]
    const short8* __restrict__ frag,         // [12*64] prebuilt B-fragments
    const float* __restrict__ Wb,            // [10]
    const int*   __restrict__ src,           // [E]
    const int*   __restrict__ dst,           // [E]
    float* __restrict__ out,                 // [E,10]
    int E)
{
    const int l = threadIdx.x;        // 0..63
    const int n = l & 15;             // A-row (edge-in-tile) AND B-col (class)
    const int q = l >> 4;             // k-quad: k = q*8 + j

    // B-fragments: 12 coalesced 16B loads, resident for all tiles
    short8 bf[NFRAG];
#pragma unroll
    for (int t = 0; t < NFRAG; ++t) bf[t] = frag[t * 64 + l];
    const float bias = (n < NC) ? Wb[n] : 0.f;

    const long tile0 = (long)blockIdx.x * TPW;

#pragma unroll 1
    for (int tt = 0; tt < TPW; ++tt) {
        const long base = (tile0 + tt) * 16;
        if (base >= E) break;                       // uniform
        const long e  = base + n;
        const long ec = (e < E) ? e : (long)(E - 1);
        const int  sA = src[ec];
        const int  dA = dst[ec];
        const float* pe = eh + ec * 128 + q * 8;

        f32x4 acc = {0.f, 0.f, 0.f, 0.f};
        f32x4 z0,z1,z2,z3,z4,z5,z6,z7;            // eh group (f32)

        if constexpr (BF16H) {
            // one h row = 128 bf16 = 256 B; lane slice: 16 B at q*16 + t*64
            const short8* ps = (const short8*)(hb + (size_t)sA * 128 + q * 8);
            const short8* pd = (const short8*)(hb + (size_t)dA * 128 + q * 8);
            short8 s0,s1,s2,s3, d0,d1,d2,d3;
            // issue src, dst, eh -- consume in the same order
            s0 = ps[0]; s1 = ps[4]; s2 = ps[8]; s3 = ps[12];
            d0 = pd[0]; d1 = pd[4]; d2 = pd[8]; d3 = pd[12];
            LGF(z0,z1,z2,z3,z4,z5,z6,z7, pe)
            acc = __builtin_amdgcn_mfma_f32_16x16x32_bf16(s0, bf[0], acc, 0,0,0);
            acc = __builtin_amdgcn_mfma_f32_16x16x32_bf16(s1, bf[1], acc, 0,0,0);
            acc = __builtin_amdgcn_mfma_f32_16x16x32_bf16(s2, bf[2], acc, 0,0,0);
            acc = __builtin_amdgcn_mfma_f32_16x16x32_bf16(s3, bf[3], acc, 0,0,0);
            acc = __builtin_amdgcn_mfma_f32_16x16x32_bf16(d0, bf[4], acc, 0,0,0);
            acc = __builtin_amdgcn_mfma_f32_16x16x32_bf16(d1, bf[5], acc, 0,0,0);
            acc = __builtin_amdgcn_mfma_f32_16x16x32_bf16(d2, bf[6], acc, 0,0,0);
            acc = __builtin_amdgcn_mfma_f32_16x16x32_bf16(d3, bf[7], acc, 0,0,0);
        } else {
            const float* ps = h + (long)sA * 128 + q * 8;
            const float* pd = h + (long)dA * 128 + q * 8;
            f32x4 x0,x1,x2,x3,x4,x5,x6,x7;
            f32x4 y0,y1,y2,y3,y4,y5,y6,y7;
            LGF(x0,x1,x2,x3,x4,x5,x6,x7, ps)
            LGF(y0,y1,y2,y3,y4,y5,y6,y7, pd)
            LGF(z0,z1,z2,z3,z4,z5,z6,z7, pe)
            acc = __builtin_amdgcn_mfma_f32_16x16x32_bf16(cvt8(x0,x1), bf[0], acc, 0,0,0);
            acc = __builtin_amdgcn_mfma_f32_16x16x32_bf16(cvt8(x2,x3), bf[1], acc, 0,0,0);
            acc = __builtin_amdgcn_mfma_f32_16x16x32_bf16(cvt8(x4,x5), bf[2], acc, 0,0,0);
            acc = __builtin_amdgcn_mfma_f32_16x16x32_bf16(cvt8(x6,x7), bf[3], acc, 0,0,0);
            acc = __builtin_amdgcn_mfma_f32_16x16x32_bf16(cvt8(y0,y1), bf[4], acc, 0,0,0);
            acc = __builtin_amdgcn_mfma_f32_16x16x32_bf16(cvt8(y2,y3), bf[5], acc, 0,0,0);
            acc = __builtin_amdgcn_mfma_f32_16x16x32_bf16(cvt8(y4,y5), bf[6], acc, 0,0,0);
            acc = __builtin_amdgcn_mfma_f32_16x16x32_bf16(cvt8(y6,y7), bf[7], acc, 0,0,0);
        }
        acc = __builtin_amdgcn_mfma_f32_16x16x32_bf16(cvt8(z0,z1), bf[8],  acc, 0,0,0);
        acc = __builtin_amdgcn_mfma_f32_16x16x32_bf16(cvt8(z2,z3), bf[9],  acc, 0,0,0);
        acc = __builtin_amdgcn_mfma_f32_16x16x32_bf16(cvt8(z4,z5), bf[10], acc, 0,0,0);
        acc = __builtin_amdgcn_mfma_f32_16x16x32_bf16(cvt8(z6,z7), bf[11], acc, 0,0,0);

        // C/D: col = n = lane&15 (class), row(edge-in-tile) = q*4 + r
        if (n < NC) {
#pragma unroll
            for (int r = 0; r < 4; ++r) {
                const long e2 = base + q * 4 + r;
                if (e2 < E) out[e2 * NC + n] = acc[r] + bias;
            }
        }
    }
}

extern "C" void kernel_launch(void* const* d_in, const int* in_sizes, int n_in,
                              void* d_out, int out_size, void* d_ws, size_t ws_size,
                              hipStream_t stream) {
    const float* h   = (const float*)d_in[0];
    const float* eh  = (const float*)d_in[1];
    const float* Ww  = (const float*)d_in[2];
    const float* Wb  = (const float*)d_in[3];
    const int*   src = (const int*)d_in[4];
    const int*   dst = (const int*)d_in[5];
    float* out = (float*)d_out;

    const int E    = in_sizes[4];
    const int N128 = in_sizes[0];                  // N * 128 elements of h

    short8* frag = (short8*)d_ws;
    build_wfrag<<<1, 64, 0, stream>>>(Ww, frag);

    const int edgesPerBlock = 16 * TPW;            // 64
    const int blocks = (E + edgesPerBlock - 1) / edgesPerBlock;  // 9375

    const size_t need = (size_t)FRAG_BYTES + (size_t)N128 * 2;
    if (ws_size >= need) {
        unsigned short* hb = (unsigned short*)((char*)d_ws + FRAG_BYTES);
        const long n8 = (long)N128 / 8;
        cvt_h_kernel<<<(int)((n8 + 255) / 256), 256, 0, stream>>>(h, (short8*)hb, n8);
        mlp_edge_mfma<true><<<blocks, 64, 0, stream>>>(h, hb, eh, frag, Wb, src, dst, out, E);
    } else {
        mlp_edge_mfma<false><<<blocks, 64, 0, stream>>>(h, nullptr, eh, frag, Wb, src, dst, out, E);
    }
}